// Round 3
// baseline (157.015 us; speedup 1.0000x reference)
//
#include <hip/hip_runtime.h>
#include <hip/hip_bf16.h>
#include <math.h>

#define NB 8
#define NL 128
#define IND 512
#define OUTD 512
#define DEPN 45
#define DEPD 16
#define W1COLS (IND + DEPD)   // 528

// ---------------- K_PREP: fused Y1/Y2/Ew + W-transpose + hpa ----------------
// blocks [0,45)        : Y1,Y2 (45x512), Ew[t]
// blocks [45,237)      : transpose W1h/W2h/Wg -> Wt[m][d][o] via 64x64 LDS tile
// blocks [237,301)     : hpa[row][d] = h[row][d] * wpos(row)
__global__ __launch_bounds__(256) void k_prep(
    const float* __restrict__ h, const unsigned char* __restrict__ mask,
    const float* __restrict__ emb,
    const float* __restrict__ W1, const float* __restrict__ W2,
    const float* __restrict__ Wg,
    float* __restrict__ hpa, float* __restrict__ Wt,
    float* __restrict__ Y1, float* __restrict__ Y2, float* __restrict__ Ew) {
    int bid = blockIdx.x;
    int tid = threadIdx.x;

    if (bid < DEPN) {
        // ---- Y1,Y2,Ew ----
        int t = bid;
        __shared__ float es[DEPD];
        __shared__ float red[4];
        if (tid < DEPD) es[tid] = emb[t * DEPD + tid];
        __syncthreads();
        float p = 0.f;
        for (int half = 0; half < 2; half++) {
            int o = tid + half * 256;
            float y1 = 0.f, y2 = 0.f;
#pragma unroll
            for (int e = 0; e < DEPD; e++) {
                y1 += es[e] * W1[o * W1COLS + IND + e];
                y2 += es[e] * W2[o * W1COLS + IND + e];
            }
            Y1[t * OUTD + o] = y1;
            Y2[t * OUTD + o] = y2;
            p += y1 * y2;
        }
        for (int off = 32; off; off >>= 1) p += __shfl_down(p, off, 64);
        if ((tid & 63) == 0) red[tid >> 6] = p;
        __syncthreads();
        if (tid == 0) Ew[t] = red[0] + red[1] + red[2] + red[3];
    } else if (bid < DEPN + 192) {
        // ---- transpose: W[o][d] -> Wt[m][d][o], 64x64 tiles ----
        int tile = bid - DEPN;
        int m = tile >> 6;            // 0..2
        int t = tile & 63;
        int orow = (t >> 3) * 64;     // o base
        int dcol = (t & 7) * 64;      // d base
        const float* W = (m == 0) ? W1 : (m == 1) ? W2 : Wg;
        int stride = (m == 2) ? IND : W1COLS;
        __shared__ float tl[64][65];
        int tx = tid & 63, ty = tid >> 6;
#pragma unroll
        for (int r = 0; r < 64; r += 4)
            tl[ty + r][tx] = W[(size_t)(orow + ty + r) * stride + dcol + tx];
        __syncthreads();
        float* Wm = Wt + (size_t)m * IND * OUTD;
#pragma unroll
        for (int r = 0; r < 64; r += 4)
            Wm[(size_t)(dcol + ty + r) * OUTD + orow + tx] = tl[tx][ty + r];
    } else {
        // ---- hpa: 16 rows each ----
        int blk = bid - (DEPN + 192);   // 0..63
        int rb = blk * 16;              // global row base (all rows same b)
        int b = rb >> 7;
        __shared__ int sflag, smin, smax;
        __shared__ float w16[16];
        if (tid == 0) { sflag = 0; smin = NL; smax = -1; }
        __syncthreads();
        const int* mi = (const int*)mask;
        if (tid < 128) {
            int v0 = mi[tid], v1 = mi[tid + 128];
            if ((unsigned)v0 > 1u || (unsigned)v1 > 1u) atomicOr(&sflag, 1);
        }
        __syncthreads();
        if (tid < 128) {
            int mval = sflag ? (int)mask[b * NL + tid] : mi[b * NL + tid];
            if (mval) { atomicMin(&smin, tid); atomicMax(&smax, tid); }
        }
        __syncthreads();
        if (tid < 16) {
            int any = (smax >= 0);
            int s = any ? smin : 0;
            int e = any ? smax : (NL - 1);
            int i = (rb & 127) + tid;
            const float invL = 1.0f / (float)NL;
            float w;
            if (i < s)      w = 1.0f - (float)(s - i) * invL;
            else if (i > e) w = 1.0f - (float)(i - e) * invL;
            else            w = 0.0f;
            int mval = sflag ? (int)mask[b * NL + i] : mi[b * NL + i];
            if (mval) w = 0.0f;
            w16[tid] = w;
        }
        __syncthreads();
        for (int idx = tid; idx < 16 * 128; idx += 256) {
            int r = idx >> 7, dc = (idx & 127) << 2;
            float4 hv = *(const float4*)&h[(size_t)(rb + r) * IND + dc];
            float wv = w16[r];
            hv.x *= wv; hv.y *= wv; hv.z *= wv; hv.w *= wv;
            *(float4*)&hpa[(size_t)(rb + r) * IND + dc] = hv;
        }
    }
}

// ---------------- K3: Pout[m] = hpa @ Wt[m] + b[m] ----------------
// No LDS, no barriers. 128 threads = 32 colthreads (2 cols, float2) x 4
// rowgroups (4 rows). Tile 16 rows x 64 cols. Grid 64x8x3 = 1536 blocks
// = 6 blocks/CU = 3 waves/SIMD.
__global__ __launch_bounds__(128) void k3_gemm(
    const float* __restrict__ hpa, const float* __restrict__ Wt,
    const float* __restrict__ b1, const float* __restrict__ b2,
    const float* __restrict__ bg,
    float* __restrict__ Pout) {
    int rb = blockIdx.x * 16;
    int cb = blockIdx.y * 64;
    int m  = blockIdx.z;
    int tid = threadIdx.x;
    int c = tid & 31, g = tid >> 5;
    int col = cb + c * 2;
    int row0 = rb + g * 4;
    const float* Wp = Wt + (size_t)m * IND * OUTD + col;
    const float* hp = hpa + (size_t)row0 * IND;

    float acc[4][2];
#pragma unroll
    for (int r = 0; r < 4; r++) { acc[r][0] = 0.f; acc[r][1] = 0.f; }

#pragma unroll 4
    for (int d = 0; d < IND; d += 4) {
        float2 w0 = *(const float2*)(Wp + (size_t)(d + 0) * OUTD);
        float2 w1 = *(const float2*)(Wp + (size_t)(d + 1) * OUTD);
        float2 w2 = *(const float2*)(Wp + (size_t)(d + 2) * OUTD);
        float2 w3 = *(const float2*)(Wp + (size_t)(d + 3) * OUTD);
        float4 h0 = *(const float4*)(hp + 0 * IND + d);
        float4 h1 = *(const float4*)(hp + 1 * IND + d);
        float4 h2 = *(const float4*)(hp + 2 * IND + d);
        float4 h3 = *(const float4*)(hp + 3 * IND + d);
        acc[0][0] += h0.x * w0.x + h0.y * w1.x + h0.z * w2.x + h0.w * w3.x;
        acc[0][1] += h0.x * w0.y + h0.y * w1.y + h0.z * w2.y + h0.w * w3.y;
        acc[1][0] += h1.x * w0.x + h1.y * w1.x + h1.z * w2.x + h1.w * w3.x;
        acc[1][1] += h1.x * w0.y + h1.y * w1.y + h1.z * w2.y + h1.w * w3.y;
        acc[2][0] += h2.x * w0.x + h2.y * w1.x + h2.z * w2.x + h2.w * w3.x;
        acc[2][1] += h2.x * w0.y + h2.y * w1.y + h2.z * w2.y + h2.w * w3.y;
        acc[3][0] += h3.x * w0.x + h3.y * w1.x + h3.z * w2.x + h3.w * w3.x;
        acc[3][1] += h3.x * w0.y + h3.y * w1.y + h3.z * w2.y + h3.w * w3.y;
    }

    const float* bb = (m == 0) ? b1 : (m == 1) ? b2 : bg;
    float2 bv = *(const float2*)&bb[col];
#pragma unroll
    for (int r = 0; r < 4; r++) {
        float2 o;
        o.x = acc[r][0] + bv.x;
        o.y = acc[r][1] + bv.y;
        *(float2*)&Pout[(size_t)m * 1024 * OUTD + (size_t)(row0 + r) * OUTD + col] = o;
    }
}

// ---------------- K5: per-row scores + normalize + A@HT + relu ----------------
__global__ __launch_bounds__(256) void k5_out(
    const float* __restrict__ P1, const float* __restrict__ P2,
    const float* __restrict__ Y1, const float* __restrict__ Y2,
    const float* __restrict__ Ew, const int* __restrict__ dep,
    const float* __restrict__ HT, const float* __restrict__ bias,
    float* __restrict__ out) {
    int row = blockIdx.x;        // 1024
    int b = row >> 7, i = row & 127;
    int tid = threadIdx.x;       // 256
    __shared__ float ps1[512], ps2[512];
    __shared__ float pd1[DEPN][4], pd2[DEPN][4];
    __shared__ float comb[DEPN];
    __shared__ float a[NL];
    __shared__ float red[4];
    __shared__ float c0s, sumv;

    ps1[tid] = P1[row * 512 + tid];
    ps1[tid + 256] = P1[row * 512 + tid + 256];
    ps2[tid] = P2[row * 512 + tid];
    ps2[tid + 256] = P2[row * 512 + tid + 256];
    __syncthreads();

    // c0 = P1 · P2
    float lc = ps1[tid] * ps2[tid] + ps1[tid + 256] * ps2[tid + 256];
    for (int off = 32; off; off >>= 1) lc += __shfl_down(lc, off, 64);
    int wid = tid >> 6, lane = tid & 63;
    if (lane == 0) red[wid] = lc;
    __syncthreads();
    if (tid == 0) c0s = red[0] + red[1] + red[2] + red[3];

    // d1[t] = P1 · Y2[t],  d2[t] = Y1[t] · P2
    if (tid < DEPN * 4) {
        int t = tid >> 2, q = tid & 3;
        const float* y1p = Y1 + t * 512 + q * 128;
        const float* y2p = Y2 + t * 512 + q * 128;
        const float* p1p = ps1 + q * 128;
        const float* p2p = ps2 + q * 128;
        float s1 = 0.f, s2 = 0.f;
#pragma unroll 4
        for (int o = 0; o < 128; o++) {
            s1 += p1p[o] * y2p[o];
            s2 += y1p[o] * p2p[o];
        }
        pd1[t][q] = s1;
        pd2[t][q] = s2;
    }
    __syncthreads();
    if (tid < DEPN) {
        comb[tid] = pd1[tid][0] + pd1[tid][1] + pd1[tid][2] + pd1[tid][3]
                  + pd2[tid][0] + pd2[tid][1] + pd2[tid][2] + pd2[tid][3]
                  + Ew[tid];
    }
    __syncthreads();

    float c0v = c0s;
    if (tid < NL) {
        int tt = dep[(b * NL + i) * NL + tid];
        float sc = 0.0f;
        if (tt != 0) sc = expf(c0v + comb[tt]);
        a[tid] = sc;
    }
    __syncthreads();
    if (tid < 64) {
        float v = a[tid] + a[tid + 64];
        for (int off = 32; off; off >>= 1) v += __shfl_down(v, off, 64);
        if (tid == 0) sumv = v;
    }
    __syncthreads();
    float inv = 1.0f / (sumv + 1e-6f);
    if (tid < NL) a[tid] *= inv;
    __syncthreads();

    // out[row, :] = relu(A_row @ HT[b] + bias)
    const float* htb = HT + b * NL * 512;
    float acc0 = bias[tid];
    float acc1 = bias[tid + 256];
#pragma unroll 8
    for (int j = 0; j < NL; j++) {
        float av = a[j];
        acc0 += av * htb[j * 512 + tid];
        acc1 += av * htb[j * 512 + tid + 256];
    }
    out[row * 512 + tid] = fmaxf(acc0, 0.0f);
    out[row * 512 + tid + 256] = fmaxf(acc1, 0.0f);
}

extern "C" void kernel_launch(void* const* d_in, const int* in_sizes, int n_in,
                              void* d_out, int out_size, void* d_ws, size_t ws_size,
                              hipStream_t stream) {
    const float* h    = (const float*)d_in[0];
    const int* dep    = (const int*)d_in[1];
    const unsigned char* mask = (const unsigned char*)d_in[2];
    const float* emb  = (const float*)d_in[3];
    const float* W1   = (const float*)d_in[4];
    const float* b1   = (const float*)d_in[5];
    const float* W2   = (const float*)d_in[6];
    const float* b2   = (const float*)d_in[7];
    const float* Wg   = (const float*)d_in[8];
    const float* bg   = (const float*)d_in[9];
    const float* bias = (const float*)d_in[10];
    float* out = (float*)d_out;

    float* ws = (float*)d_ws;
    float* hpa = ws;                  // 524288
    float* Wt  = hpa + 524288;        // 3 * 262144 = 786432
    float* Y1  = Wt + 786432;         // 23040
    float* Y2  = Y1 + 23040;          // 23040
    float* Ew  = Y2 + 23040;          // 64
    float* P   = Ew + 64;             // 3 * 524288
    float* P1  = P;
    float* P2  = P + 524288;
    float* HT  = P + 1048576;

    k_prep<<<DEPN + 192 + 64, 256, 0, stream>>>(h, mask, emb, W1, W2, Wg,
                                                hpa, Wt, Y1, Y2, Ew);
    dim3 g3(64, 8, 3);
    k3_gemm<<<g3, 128, 0, stream>>>(hpa, Wt, b1, b2, bg, P);
    k5_out<<<NB * NL, 256, 0, stream>>>(P1, P2, Y1, Y2, Ew, dep, HT, bias, out);
}

// Round 4
// 144.094 us; speedup vs baseline: 1.0897x; 1.0897x over previous
//
#include <hip/hip_runtime.h>
#include <math.h>

#define NBATCH 8
#define NL 128
#define IND 512
#define DEPN 45
#define DEPD 16
#define WCOLS 528          // IN_DIM + DEP_DIM
#define NP 1664            // extended GEMM width
#define C_P1 0
#define C_P2 512
#define C_HT 1024
#define C_D1 1536
#define C_D2 1581
#define C_PAD 1626

// ================= k_prep =================
// blocks [0,45):    Y1,Y2 (45x512), Ew[t]
// blocks [45,237):  transpose W1h/W2h/Wg -> Wt[d][m*512+o]
// blocks [237,301): hpa[row][d] = h[row][d] * wpos(row)
__global__ __launch_bounds__(256) void k_prep(
    const float* __restrict__ h, const unsigned char* __restrict__ mask,
    const float* __restrict__ emb,
    const float* __restrict__ W1, const float* __restrict__ W2,
    const float* __restrict__ Wg,
    float* __restrict__ hpa, float* __restrict__ Wt,
    float* __restrict__ Y1, float* __restrict__ Y2, float* __restrict__ Ew) {
    int bid = blockIdx.x;
    int tid = threadIdx.x;

    if (bid < DEPN) {
        int t = bid;
        __shared__ float es[DEPD];
        __shared__ float red[4];
        if (tid < DEPD) es[tid] = emb[t * DEPD + tid];
        __syncthreads();
        float p = 0.f;
        for (int half = 0; half < 2; half++) {
            int o = tid + half * 256;
            float y1 = 0.f, y2 = 0.f;
#pragma unroll
            for (int e = 0; e < DEPD; e++) {
                y1 += es[e] * W1[o * WCOLS + IND + e];
                y2 += es[e] * W2[o * WCOLS + IND + e];
            }
            Y1[t * 512 + o] = y1;
            Y2[t * 512 + o] = y2;
            p += y1 * y2;
        }
        for (int off = 32; off; off >>= 1) p += __shfl_down(p, off, 64);
        if ((tid & 63) == 0) red[tid >> 6] = p;
        __syncthreads();
        if (tid == 0) Ew[t] = red[0] + red[1] + red[2] + red[3];
    } else if (bid < DEPN + 192) {
        int tile = bid - DEPN;
        int m = tile >> 6;
        int t = tile & 63;
        int orow = (t >> 3) * 64;
        int dcol = (t & 7) * 64;
        const float* W = (m == 0) ? W1 : (m == 1) ? W2 : Wg;
        int stride = (m == 2) ? IND : WCOLS;
        __shared__ float tl[64][65];
        int tx = tid & 63, ty = tid >> 6;
#pragma unroll
        for (int r = 0; r < 64; r += 4)
            tl[ty + r][tx] = W[(size_t)(orow + ty + r) * stride + dcol + tx];
        __syncthreads();
#pragma unroll
        for (int r = 0; r < 64; r += 4)
            Wt[(size_t)(dcol + ty + r) * NP + m * 512 + orow + tx] = tl[tx][ty + r];
    } else {
        int blk = bid - (DEPN + 192);
        int rb = blk * 16;
        int b = rb >> 7;
        __shared__ int sflag, smin, smax;
        __shared__ float w16[16];
        if (tid == 0) { sflag = 0; smin = NL; smax = -1; }
        __syncthreads();
        const int* mi = (const int*)mask;
        if (tid < 128) {
            int v0 = mi[tid], v1 = mi[tid + 128];
            if ((unsigned)v0 > 1u || (unsigned)v1 > 1u) atomicOr(&sflag, 1);
        }
        __syncthreads();
        if (tid < 128) {
            int mval = sflag ? (int)mask[b * NL + tid] : mi[b * NL + tid];
            if (mval) { atomicMin(&smin, tid); atomicMax(&smax, tid); }
        }
        __syncthreads();
        if (tid < 16) {
            int any = (smax >= 0);
            int s = any ? smin : 0;
            int e = any ? smax : (NL - 1);
            int i = (rb & 127) + tid;
            const float invL = 1.0f / (float)NL;
            float w;
            if (i < s)      w = 1.0f - (float)(s - i) * invL;
            else if (i > e) w = 1.0f - (float)(i - e) * invL;
            else            w = 0.0f;
            int mval = sflag ? (int)mask[b * NL + i] : mi[b * NL + i];
            if (mval) w = 0.0f;
            w16[tid] = w;
        }
        __syncthreads();
        for (int idx = tid; idx < 16 * 128; idx += 256) {
            int r = idx >> 7, dc = (idx & 127) << 2;
            float4 hv = *(const float4*)&h[(size_t)(rb + r) * IND + dc];
            float wv = w16[r];
            hv.x *= wv; hv.y *= wv; hv.z *= wv; hv.w *= wv;
            *(float4*)&hpa[(size_t)(rb + r) * IND + dc] = hv;
        }
    }
}

// ================= k_prep2: Z columns + bias_ext =================
// blocks [0,45): Wt[d][C_D1+t] = W1h^T row d . Y2[t];  Wt[d][C_D2+t] = W2h^T row d . Y1[t]
//               bias_ext[C_D1+t] = b1.Y2[t] + Ew[t];  bias_ext[C_D2+t] = b2.Y1[t]
// block 45:     copy b1,b2,bg into bias_ext; zero pad cols of Wt and bias_ext
__device__ inline float dot4v(float4 a, const float* y) {
    return a.x * y[0] + a.y * y[1] + a.z * y[2] + a.w * y[3];
}
__global__ __launch_bounds__(256) void k_prep2(
    const float* __restrict__ b1, const float* __restrict__ b2,
    const float* __restrict__ bg,
    const float* __restrict__ Y1, const float* __restrict__ Y2,
    const float* __restrict__ Ew,
    float* __restrict__ Wt, float* __restrict__ bias_ext) {
    int t = blockIdx.x;
    int tid = threadIdx.x;
    if (t < DEPN) {
        __shared__ float y1s[512], y2s[512];
        y1s[tid] = Y1[t * 512 + tid]; y1s[tid + 256] = Y1[t * 512 + tid + 256];
        y2s[tid] = Y2[t * 512 + tid]; y2s[tid + 256] = Y2[t * 512 + tid + 256];
        __syncthreads();
        int w = tid >> 6, l = tid & 63;
        for (int d = w; d < 512; d += 4) {
            const float* wr = Wt + (size_t)d * NP;
            float4 wa = *(const float4*)(wr + l * 4);
            float4 wb = *(const float4*)(wr + l * 4 + 256);
            float4 va = *(const float4*)(wr + 512 + l * 4);
            float4 vb = *(const float4*)(wr + 512 + l * 4 + 256);
            float z2 = dot4v(wa, &y2s[l * 4]) + dot4v(wb, &y2s[l * 4 + 256]);
            float z1 = dot4v(va, &y1s[l * 4]) + dot4v(vb, &y1s[l * 4 + 256]);
            for (int off = 32; off; off >>= 1) {
                z2 += __shfl_down(z2, off, 64);
                z1 += __shfl_down(z1, off, 64);
            }
            if (l == 0) {
                Wt[(size_t)d * NP + C_D1 + t] = z2;
                Wt[(size_t)d * NP + C_D2 + t] = z1;
            }
        }
        // biasD
        if (tid < 128) {
            int ww = tid >> 6, ll = tid & 63;
            const float* bb = ww ? b2 : b1;
            const float* ys = ww ? y1s : y2s;
            float s = 0.f;
            for (int k = ll; k < 512; k += 64) s += bb[k] * ys[k];
            for (int off = 32; off; off >>= 1) s += __shfl_down(s, off, 64);
            if (ll == 0) {
                if (ww == 0) bias_ext[C_D1 + t] = s + Ew[t];
                else         bias_ext[C_D2 + t] = s;
            }
        }
    } else {
        for (int i = tid; i < 512; i += 256) {
            bias_ext[C_P1 + i] = b1[i];
            bias_ext[C_P2 + i] = b2[i];
            bias_ext[C_HT + i] = bg[i];
        }
        for (int i = tid; i < NP - C_PAD; i += 256) bias_ext[C_PAD + i] = 0.f;
        for (int idx = tid; idx < 512 * (NP - C_PAD); idx += 256) {
            int d = idx / (NP - C_PAD), c = idx % (NP - C_PAD);
            Wt[(size_t)d * NP + C_PAD + c] = 0.f;
        }
    }
}

// ================= k3: Pout = hpa @ Wt + bias_ext =================
// Tile 16 rows x 128 cols, 128 threads (32 colthreads x 4 rowgroups),
// 4x4 outputs/thread, register double-buffered W loads.
#define ACCR(A, H, W0, W1_, W2_, W3_) \
    A.x += H.x*W0.x + H.y*W1_.x + H.z*W2_.x + H.w*W3_.x; \
    A.y += H.x*W0.y + H.y*W1_.y + H.z*W2_.y + H.w*W3_.y; \
    A.z += H.x*W0.z + H.y*W1_.z + H.z*W2_.z + H.w*W3_.z; \
    A.w += H.x*W0.w + H.y*W1_.w + H.z*W2_.w + H.w*W3_.w;

__global__ __launch_bounds__(128) void k3_gemm(
    const float* __restrict__ hpa, const float* __restrict__ Wt,
    const float* __restrict__ bias_ext, float* __restrict__ Pout) {
    int rb = blockIdx.x * 16;
    int cb = blockIdx.y * 128;
    int tid = threadIdx.x;
    int c = tid & 31, g4 = (tid >> 5) << 2;
    int col = cb + c * 4;

    __shared__ float hs[16][IND];   // 32 KB
    {
        const float4* src = (const float4*)(hpa + (size_t)rb * IND);
        float4* dst = (float4*)&hs[0][0];
#pragma unroll
        for (int i = 0; i < 16; i++) dst[tid + i * 128] = src[tid + i * 128];
    }
    __syncthreads();

    float4 z = {0.f, 0.f, 0.f, 0.f};
    float4 acc0 = z, acc1 = z, acc2 = z, acc3 = z;
    const float* Wp = Wt + col;

    float4 wa0 = *(const float4*)(Wp + (size_t)0 * NP);
    float4 wa1 = *(const float4*)(Wp + (size_t)1 * NP);
    float4 wa2 = *(const float4*)(Wp + (size_t)2 * NP);
    float4 wa3 = *(const float4*)(Wp + (size_t)3 * NP);

    for (int d = 0; d < IND; d += 8) {
        float4 wb0 = *(const float4*)(Wp + (size_t)(d + 4) * NP);
        float4 wb1 = *(const float4*)(Wp + (size_t)(d + 5) * NP);
        float4 wb2 = *(const float4*)(Wp + (size_t)(d + 6) * NP);
        float4 wb3 = *(const float4*)(Wp + (size_t)(d + 7) * NP);
        {
            float4 h0 = *(const float4*)&hs[g4 + 0][d];
            float4 h1 = *(const float4*)&hs[g4 + 1][d];
            float4 h2 = *(const float4*)&hs[g4 + 2][d];
            float4 h3 = *(const float4*)&hs[g4 + 3][d];
            ACCR(acc0, h0, wa0, wa1, wa2, wa3)
            ACCR(acc1, h1, wa0, wa1, wa2, wa3)
            ACCR(acc2, h2, wa0, wa1, wa2, wa3)
            ACCR(acc3, h3, wa0, wa1, wa2, wa3)
        }
        int dn = (d + 8) & (IND - 1);   // last iter: dummy row 0
        wa0 = *(const float4*)(Wp + (size_t)(dn + 0) * NP);
        wa1 = *(const float4*)(Wp + (size_t)(dn + 1) * NP);
        wa2 = *(const float4*)(Wp + (size_t)(dn + 2) * NP);
        wa3 = *(const float4*)(Wp + (size_t)(dn + 3) * NP);
        {
            float4 h0 = *(const float4*)&hs[g4 + 0][d + 4];
            float4 h1 = *(const float4*)&hs[g4 + 1][d + 4];
            float4 h2 = *(const float4*)&hs[g4 + 2][d + 4];
            float4 h3 = *(const float4*)&hs[g4 + 3][d + 4];
            ACCR(acc0, h0, wb0, wb1, wb2, wb3)
            ACCR(acc1, h1, wb0, wb1, wb2, wb3)
            ACCR(acc2, h2, wb0, wb1, wb2, wb3)
            ACCR(acc3, h3, wb0, wb1, wb2, wb3)
        }
    }

    float4 bv = *(const float4*)(bias_ext + col);
    float4 o0, o1, o2, o3;
    o0.x = acc0.x + bv.x; o0.y = acc0.y + bv.y; o0.z = acc0.z + bv.z; o0.w = acc0.w + bv.w;
    o1.x = acc1.x + bv.x; o1.y = acc1.y + bv.y; o1.z = acc1.z + bv.z; o1.w = acc1.w + bv.w;
    o2.x = acc2.x + bv.x; o2.y = acc2.y + bv.y; o2.z = acc2.z + bv.z; o2.w = acc2.w + bv.w;
    o3.x = acc3.x + bv.x; o3.y = acc3.y + bv.y; o3.z = acc3.z + bv.z; o3.w = acc3.w + bv.w;
    *(float4*)&Pout[(size_t)(rb + g4 + 0) * NP + col] = o0;
    *(float4*)&Pout[(size_t)(rb + g4 + 1) * NP + col] = o1;
    *(float4*)&Pout[(size_t)(rb + g4 + 2) * NP + col] = o2;
    *(float4*)&Pout[(size_t)(rb + g4 + 3) * NP + col] = o3;
}

// ================= k5: scores lookup + normalize + A@HT + relu =================
__global__ __launch_bounds__(128) void k5_out(
    const float* __restrict__ P, const int* __restrict__ dep,
    const float* __restrict__ bias, float* __restrict__ out) {
    int row = blockIdx.x;        // 1024
    int b = row >> 7;
    int tid = threadIdx.x;       // 128
    __shared__ float comb[DEPN];
    __shared__ float a[NL];
    __shared__ float red[2];
    __shared__ float sumv;

    const float* Prow = P + (size_t)row * NP;
    // c0 = P1 . P2
    float4 p1 = *(const float4*)(Prow + C_P1 + tid * 4);
    float4 p2 = *(const float4*)(Prow + C_P2 + tid * 4);
    float lc = p1.x * p2.x + p1.y * p2.y + p1.z * p2.z + p1.w * p2.w;
    for (int off = 32; off; off >>= 1) lc += __shfl_down(lc, off, 64);
    if ((tid & 63) == 0) red[tid >> 6] = lc;
    if (tid < DEPN) comb[tid] = Prow[C_D1 + tid] + Prow[C_D2 + tid];
    __syncthreads();

    float c0 = red[0] + red[1];
    int tt = dep[(size_t)row * NL + tid];
    float sc = (tt != 0) ? expf(c0 + comb[tt]) : 0.f;
    a[tid] = sc;
    __syncthreads();
    if (tid < 64) {
        float v = a[tid] + a[tid + 64];
        for (int off = 32; off; off >>= 1) v += __shfl_down(v, off, 64);
        if (tid == 0) sumv = v;
    }
    __syncthreads();
    float inv = 1.0f / (sumv + 1e-6f);

    // out = relu(inv * sum_j a[j]*HT[b,j,:] + bias)
    const float* htb = P + (size_t)b * NL * NP + C_HT + tid * 4;
    float sx = 0.f, sy = 0.f, sz = 0.f, sw = 0.f;
#pragma unroll 4
    for (int j = 0; j < NL; j += 2) {
        float a0 = a[j], a1 = a[j + 1];
        float4 v0 = *(const float4*)(htb + (size_t)j * NP);
        float4 v1 = *(const float4*)(htb + (size_t)(j + 1) * NP);
        sx += a0 * v0.x + a1 * v1.x;
        sy += a0 * v0.y + a1 * v1.y;
        sz += a0 * v0.z + a1 * v1.z;
        sw += a0 * v0.w + a1 * v1.w;
    }
    float4 bv = *(const float4*)&bias[tid * 4];
    float4 o;
    o.x = fmaxf(sx * inv + bv.x, 0.f);
    o.y = fmaxf(sy * inv + bv.y, 0.f);
    o.z = fmaxf(sz * inv + bv.z, 0.f);
    o.w = fmaxf(sw * inv + bv.w, 0.f);
    *(float4*)&out[(size_t)row * 512 + tid * 4] = o;
}

extern "C" void kernel_launch(void* const* d_in, const int* in_sizes, int n_in,
                              void* d_out, int out_size, void* d_ws, size_t ws_size,
                              hipStream_t stream) {
    const float* h    = (const float*)d_in[0];
    const int* dep    = (const int*)d_in[1];
    const unsigned char* mask = (const unsigned char*)d_in[2];
    const float* emb  = (const float*)d_in[3];
    const float* W1   = (const float*)d_in[4];
    const float* b1   = (const float*)d_in[5];
    const float* W2   = (const float*)d_in[6];
    const float* b2   = (const float*)d_in[7];
    const float* Wg   = (const float*)d_in[8];
    const float* bg   = (const float*)d_in[9];
    const float* bias = (const float*)d_in[10];
    float* out = (float*)d_out;

    float* ws = (float*)d_ws;
    float* hpa      = ws;                      // 524288
    float* Wt       = hpa + 524288;            // 512*1664 = 851968
    float* bias_ext = Wt + 851968;             // 1664
    float* Y1       = bias_ext + 1664;         // 23040
    float* Y2       = Y1 + 23040;              // 23040
    float* Ew       = Y2 + 23040;              // 64
    float* Pout     = Ew + 64;                 // 1024*1664 = 1703936

    k_prep<<<DEPN + 192 + 64, 256, 0, stream>>>(h, mask, emb, W1, W2, Wg,
                                                hpa, Wt, Y1, Y2, Ew);
    k_prep2<<<DEPN + 1, 256, 0, stream>>>(b1, b2, bg, Y1, Y2, Ew, Wt, bias_ext);
    dim3 g3(64, 13);
    k3_gemm<<<g3, 128, 0, stream>>>(hpa, Wt, bias_ext, Pout);
    k5_out<<<NBATCH * NL, 128, 0, stream>>>(Pout, dep, bias, out);
}

// Round 5
// 84.637 us; speedup vs baseline: 1.8552x; 1.7025x over previous
//
#include <hip/hip_runtime.h>
#include <math.h>

#define NBATCH 8
#define NL 128
#define IND 512
#define DEPN 45
#define DEPD 16
#define WCOLS 528          // IN_DIM + DEP_DIM
#define NP 1664            // extended GEMM width
#define C_P1 0
#define C_P2 512
#define C_HT 1024
#define C_D1 1536
#define C_D2 1581
#define C_PAD 1626

// ================= k_prep =================
// blocks [0,45):    Y1,Y2 (45x512), Ew[t]
// blocks [45,237):  transpose W1h/W2h/Wg -> Wt[d][m*512+o]
// blocks [237,301): hpa[row][d] = h[row][d] * wpos(row)
// blocks [301,365): zero Wt pad cols (8 d-rows each); blk 0 also fills bias_ext
__global__ __launch_bounds__(256) void k_prep(
    const float* __restrict__ h, const unsigned char* __restrict__ mask,
    const float* __restrict__ emb,
    const float* __restrict__ W1, const float* __restrict__ W2,
    const float* __restrict__ Wg,
    const float* __restrict__ b1, const float* __restrict__ b2,
    const float* __restrict__ bg,
    float* __restrict__ hpa, float* __restrict__ Wt,
    float* __restrict__ Y1, float* __restrict__ Y2, float* __restrict__ Ew,
    float* __restrict__ bias_ext) {
    int bid = blockIdx.x;
    int tid = threadIdx.x;

    if (bid < DEPN) {
        int t = bid;
        __shared__ float es[DEPD];
        __shared__ float red[4];
        if (tid < DEPD) es[tid] = emb[t * DEPD + tid];
        __syncthreads();
        float p = 0.f;
        for (int half = 0; half < 2; half++) {
            int o = tid + half * 256;
            float y1 = 0.f, y2 = 0.f;
#pragma unroll
            for (int e = 0; e < DEPD; e++) {
                y1 += es[e] * W1[o * WCOLS + IND + e];
                y2 += es[e] * W2[o * WCOLS + IND + e];
            }
            Y1[t * 512 + o] = y1;
            Y2[t * 512 + o] = y2;
            p += y1 * y2;
        }
        for (int off = 32; off; off >>= 1) p += __shfl_down(p, off, 64);
        if ((tid & 63) == 0) red[tid >> 6] = p;
        __syncthreads();
        if (tid == 0) Ew[t] = red[0] + red[1] + red[2] + red[3];
    } else if (bid < DEPN + 192) {
        int tile = bid - DEPN;
        int m = tile >> 6;
        int t = tile & 63;
        int orow = (t >> 3) * 64;
        int dcol = (t & 7) * 64;
        const float* W = (m == 0) ? W1 : (m == 1) ? W2 : Wg;
        int stride = (m == 2) ? IND : WCOLS;
        __shared__ float tl[64][65];
        int tx = tid & 63, ty = tid >> 6;
#pragma unroll
        for (int r = 0; r < 64; r += 4)
            tl[ty + r][tx] = W[(size_t)(orow + ty + r) * stride + dcol + tx];
        __syncthreads();
#pragma unroll
        for (int r = 0; r < 64; r += 4)
            Wt[(size_t)(dcol + ty + r) * NP + m * 512 + orow + tx] = tl[tx][ty + r];
    } else if (bid < DEPN + 192 + 64) {
        int blk = bid - (DEPN + 192);
        int rb = blk * 16;
        int b = rb >> 7;
        __shared__ int sflag, smin, smax;
        __shared__ float w16[16];
        if (tid == 0) { sflag = 0; smin = NL; smax = -1; }
        __syncthreads();
        const int* mi = (const int*)mask;
        if (tid < 128) {
            int v0 = mi[tid], v1 = mi[tid + 128];
            if ((unsigned)v0 > 1u || (unsigned)v1 > 1u) atomicOr(&sflag, 1);
        }
        __syncthreads();
        if (tid < 128) {
            int mval = sflag ? (int)mask[b * NL + tid] : mi[b * NL + tid];
            if (mval) { atomicMin(&smin, tid); atomicMax(&smax, tid); }
        }
        __syncthreads();
        if (tid < 16) {
            int any = (smax >= 0);
            int s = any ? smin : 0;
            int e = any ? smax : (NL - 1);
            int i = (rb & 127) + tid;
            const float invL = 1.0f / (float)NL;
            float w;
            if (i < s)      w = 1.0f - (float)(s - i) * invL;
            else if (i > e) w = 1.0f - (float)(i - e) * invL;
            else            w = 0.0f;
            int mval = sflag ? (int)mask[b * NL + i] : mi[b * NL + i];
            if (mval) w = 0.0f;
            w16[tid] = w;
        }
        __syncthreads();
        for (int idx = tid; idx < 16 * 128; idx += 256) {
            int r = idx >> 7, dc = (idx & 127) << 2;
            float4 hv = *(const float4*)&h[(size_t)(rb + r) * IND + dc];
            float wv = w16[r];
            hv.x *= wv; hv.y *= wv; hv.z *= wv; hv.w *= wv;
            *(float4*)&hpa[(size_t)(rb + r) * IND + dc] = hv;
        }
    } else {
        // ---- zero pad cols of Wt (8 d-rows per block); blk 0: bias_ext base ----
        int blk = bid - (DEPN + 192 + 64);   // 0..63
        int d0 = blk * 8;
        int r = tid >> 5, c = tid & 31;
        Wt[(size_t)(d0 + r) * NP + C_PAD + c] = 0.f;
        if (c < 6) Wt[(size_t)(d0 + r) * NP + C_PAD + 32 + c] = 0.f;
        if (blk == 0) {
            for (int i = tid; i < 512; i += 256) {
                bias_ext[C_P1 + i] = b1[i];
                bias_ext[C_P2 + i] = b2[i];
                bias_ext[C_HT + i] = bg[i];
            }
            if (tid < NP - C_PAD) bias_ext[C_PAD + tid] = 0.f;
        }
    }
}

// ================= k_prep2: Z columns + D-bias =================
// grid (45 t, 2 m, 4 chunk): block computes Wt[d][C_D1/C_D2 + t] for
// d in [chunk*128, chunk*128+128).  m=0: Z1 = W1h^T . Y2[t] -> C_D1;
// m=1: Z2 = W2h^T . Y1[t] -> C_D2.  chunk 0 also does the bias dot.
__global__ __launch_bounds__(256) void k_prep2(
    const float* __restrict__ b1, const float* __restrict__ b2,
    const float* __restrict__ Y1, const float* __restrict__ Y2,
    const float* __restrict__ Ew,
    float* __restrict__ Wt, float* __restrict__ bias_ext) {
    int t = blockIdx.x;
    int m = blockIdx.y;
    int chunk = blockIdx.z;
    int tid = threadIdx.x;
    int w = tid >> 6, l = tid & 63;
    __shared__ float ys[512];
    const float* Y = (m == 0) ? Y2 : Y1;
    ys[tid] = Y[t * 512 + tid];
    ys[tid + 256] = Y[t * 512 + tid + 256];
    __syncthreads();

    int dbase = chunk * 128;
    int colD = (m == 0) ? (C_D1 + t) : (C_D2 + t);
    for (int r = w; r < 128; r += 4) {
        int d = dbase + r;
        const float* wr = Wt + (size_t)d * NP + m * 512;
        float s = 0.f;
#pragma unroll
        for (int k = 0; k < 8; k++) s += wr[l + k * 64] * ys[l + k * 64];
        for (int off = 32; off; off >>= 1) s += __shfl_down(s, off, 64);
        if (l == 0) Wt[(size_t)d * NP + colD] = s;
    }

    if (chunk == 0 && tid < 64) {
        const float* bb = (m == 0) ? b1 : b2;
        float s = 0.f;
#pragma unroll
        for (int k = 0; k < 8; k++) s += bb[tid + k * 64] * ys[tid + k * 64];
        for (int off = 32; off; off >>= 1) s += __shfl_down(s, off, 64);
        if (tid == 0) {
            if (m == 0) bias_ext[C_D1 + t] = s + Ew[t];
            else        bias_ext[C_D2 + t] = s;
        }
    }
}

// ================= k3: Pout = hpa @ Wt + bias_ext =================
// Tile 16 rows x 128 cols, 128 threads (32 colthreads x 4 rowgroups),
// 4x4 outputs/thread, register double-buffered W loads.
#define ACCR(A, H, W0, W1_, W2_, W3_) \
    A.x += H.x*W0.x + H.y*W1_.x + H.z*W2_.x + H.w*W3_.x; \
    A.y += H.x*W0.y + H.y*W1_.y + H.z*W2_.y + H.w*W3_.y; \
    A.z += H.x*W0.z + H.y*W1_.z + H.z*W2_.z + H.w*W3_.z; \
    A.w += H.x*W0.w + H.y*W1_.w + H.z*W2_.w + H.w*W3_.w;

__global__ __launch_bounds__(128) void k3_gemm(
    const float* __restrict__ hpa, const float* __restrict__ Wt,
    const float* __restrict__ bias_ext, float* __restrict__ Pout) {
    int rb = blockIdx.x * 16;
    int cb = blockIdx.y * 128;
    int tid = threadIdx.x;
    int c = tid & 31, g4 = (tid >> 5) << 2;
    int col = cb + c * 4;

    __shared__ float hs[16][IND];   // 32 KB
    {
        const float4* src = (const float4*)(hpa + (size_t)rb * IND);
        float4* dst = (float4*)&hs[0][0];
#pragma unroll
        for (int i = 0; i < 16; i++) dst[tid + i * 128] = src[tid + i * 128];
    }
    __syncthreads();

    float4 z = {0.f, 0.f, 0.f, 0.f};
    float4 acc0 = z, acc1 = z, acc2 = z, acc3 = z;
    const float* Wp = Wt + col;

    float4 wa0 = *(const float4*)(Wp + (size_t)0 * NP);
    float4 wa1 = *(const float4*)(Wp + (size_t)1 * NP);
    float4 wa2 = *(const float4*)(Wp + (size_t)2 * NP);
    float4 wa3 = *(const float4*)(Wp + (size_t)3 * NP);

    for (int d = 0; d < IND; d += 8) {
        float4 wb0 = *(const float4*)(Wp + (size_t)(d + 4) * NP);
        float4 wb1 = *(const float4*)(Wp + (size_t)(d + 5) * NP);
        float4 wb2 = *(const float4*)(Wp + (size_t)(d + 6) * NP);
        float4 wb3 = *(const float4*)(Wp + (size_t)(d + 7) * NP);
        {
            float4 h0 = *(const float4*)&hs[g4 + 0][d];
            float4 h1 = *(const float4*)&hs[g4 + 1][d];
            float4 h2 = *(const float4*)&hs[g4 + 2][d];
            float4 h3 = *(const float4*)&hs[g4 + 3][d];
            ACCR(acc0, h0, wa0, wa1, wa2, wa3)
            ACCR(acc1, h1, wa0, wa1, wa2, wa3)
            ACCR(acc2, h2, wa0, wa1, wa2, wa3)
            ACCR(acc3, h3, wa0, wa1, wa2, wa3)
        }
        int dn = (d + 8) & (IND - 1);   // last iter: dummy row 0
        wa0 = *(const float4*)(Wp + (size_t)(dn + 0) * NP);
        wa1 = *(const float4*)(Wp + (size_t)(dn + 1) * NP);
        wa2 = *(const float4*)(Wp + (size_t)(dn + 2) * NP);
        wa3 = *(const float4*)(Wp + (size_t)(dn + 3) * NP);
        {
            float4 h0 = *(const float4*)&hs[g4 + 0][d + 4];
            float4 h1 = *(const float4*)&hs[g4 + 1][d + 4];
            float4 h2 = *(const float4*)&hs[g4 + 2][d + 4];
            float4 h3 = *(const float4*)&hs[g4 + 3][d + 4];
            ACCR(acc0, h0, wb0, wb1, wb2, wb3)
            ACCR(acc1, h1, wb0, wb1, wb2, wb3)
            ACCR(acc2, h2, wb0, wb1, wb2, wb3)
            ACCR(acc3, h3, wb0, wb1, wb2, wb3)
        }
    }

    float4 bv = *(const float4*)(bias_ext + col);
    float4 o0, o1, o2, o3;
    o0.x = acc0.x + bv.x; o0.y = acc0.y + bv.y; o0.z = acc0.z + bv.z; o0.w = acc0.w + bv.w;
    o1.x = acc1.x + bv.x; o1.y = acc1.y + bv.y; o1.z = acc1.z + bv.z; o1.w = acc1.w + bv.w;
    o2.x = acc2.x + bv.x; o2.y = acc2.y + bv.y; o2.z = acc2.z + bv.z; o2.w = acc2.w + bv.w;
    o3.x = acc3.x + bv.x; o3.y = acc3.y + bv.y; o3.z = acc3.z + bv.z; o3.w = acc3.w + bv.w;
    *(float4*)&Pout[(size_t)(rb + g4 + 0) * NP + col] = o0;
    *(float4*)&Pout[(size_t)(rb + g4 + 1) * NP + col] = o1;
    *(float4*)&Pout[(size_t)(rb + g4 + 2) * NP + col] = o2;
    *(float4*)&Pout[(size_t)(rb + g4 + 3) * NP + col] = o3;
}

// ================= k5: scores lookup + normalize + A@HT + relu =================
__global__ __launch_bounds__(128) void k5_out(
    const float* __restrict__ P, const int* __restrict__ dep,
    const float* __restrict__ bias, float* __restrict__ out) {
    int row = blockIdx.x;        // 1024
    int b = row >> 7;
    int tid = threadIdx.x;       // 128
    __shared__ float comb[DEPN];
    __shared__ float a[NL];
    __shared__ float red[2];
    __shared__ float sumv;

    const float* Prow = P + (size_t)row * NP;
    // c0 = P1 . P2
    float4 p1 = *(const float4*)(Prow + C_P1 + tid * 4);
    float4 p2 = *(const float4*)(Prow + C_P2 + tid * 4);
    float lc = p1.x * p2.x + p1.y * p2.y + p1.z * p2.z + p1.w * p2.w;
    for (int off = 32; off; off >>= 1) lc += __shfl_down(lc, off, 64);
    if ((tid & 63) == 0) red[tid >> 6] = lc;
    if (tid < DEPN) comb[tid] = Prow[C_D1 + tid] + Prow[C_D2 + tid];
    __syncthreads();

    float c0 = red[0] + red[1];
    int tt = dep[(size_t)row * NL + tid];
    float sc = (tt != 0) ? expf(c0 + comb[tt]) : 0.f;
    a[tid] = sc;
    __syncthreads();
    if (tid < 64) {
        float v = a[tid] + a[tid + 64];
        for (int off = 32; off; off >>= 1) v += __shfl_down(v, off, 64);
        if (tid == 0) sumv = v;
    }
    __syncthreads();
    float inv = 1.0f / (sumv + 1e-6f);

    // out = relu(inv * sum_j a[j]*HT[b,j,:] + bias)
    const float* htb = P + (size_t)b * NL * NP + C_HT + tid * 4;
    float sx = 0.f, sy = 0.f, sz = 0.f, sw = 0.f;
#pragma unroll 4
    for (int j = 0; j < NL; j += 2) {
        float a0 = a[j], a1 = a[j + 1];
        float4 v0 = *(const float4*)(htb + (size_t)j * NP);
        float4 v1 = *(const float4*)(htb + (size_t)(j + 1) * NP);
        sx += a0 * v0.x + a1 * v1.x;
        sy += a0 * v0.y + a1 * v1.y;
        sz += a0 * v0.z + a1 * v1.z;
        sw += a0 * v0.w + a1 * v1.w;
    }
    float4 bv = *(const float4*)&bias[tid * 4];
    float4 o;
    o.x = fmaxf(sx * inv + bv.x, 0.f);
    o.y = fmaxf(sy * inv + bv.y, 0.f);
    o.z = fmaxf(sz * inv + bv.z, 0.f);
    o.w = fmaxf(sw * inv + bv.w, 0.f);
    *(float4*)&out[(size_t)row * 512 + tid * 4] = o;
}

extern "C" void kernel_launch(void* const* d_in, const int* in_sizes, int n_in,
                              void* d_out, int out_size, void* d_ws, size_t ws_size,
                              hipStream_t stream) {
    const float* h    = (const float*)d_in[0];
    const int* dep    = (const int*)d_in[1];
    const unsigned char* mask = (const unsigned char*)d_in[2];
    const float* emb  = (const float*)d_in[3];
    const float* W1   = (const float*)d_in[4];
    const float* b1   = (const float*)d_in[5];
    const float* W2   = (const float*)d_in[6];
    const float* b2   = (const float*)d_in[7];
    const float* Wg   = (const float*)d_in[8];
    const float* bg   = (const float*)d_in[9];
    const float* bias = (const float*)d_in[10];
    float* out = (float*)d_out;

    float* ws = (float*)d_ws;
    float* hpa      = ws;                      // 524288
    float* Wt       = hpa + 524288;            // 512*1664 = 851968
    float* bias_ext = Wt + 851968;             // 1664
    float* Y1       = bias_ext + 1664;         // 23040
    float* Y2       = Y1 + 23040;              // 23040
    float* Ew       = Y2 + 23040;              // 64
    float* Pout     = Ew + 64;                 // 1024*1664 = 1703936

    k_prep<<<DEPN + 192 + 64 + 64, 256, 0, stream>>>(h, mask, emb, W1, W2, Wg,
                                                     b1, b2, bg,
                                                     hpa, Wt, Y1, Y2, Ew, bias_ext);
    dim3 g2(DEPN, 2, 4);
    k_prep2<<<g2, 256, 0, stream>>>(b1, b2, Y1, Y2, Ew, Wt, bias_ext);
    dim3 g3(64, 13);
    k3_gemm<<<g3, 128, 0, stream>>>(hpa, Wt, bias_ext, Pout);
    k5_out<<<NBATCH * NL, 128, 0, stream>>>(Pout, dep, bias, out);
}